// Round 11
// baseline (453.793 us; speedup 1.0000x reference)
//
#include <hip/hip_runtime.h>
#include <hip/hip_bf16.h>
#include <math.h>

#define NTOK 4096
#define DIMSZ 1024
#define HID 4096
#define NE 8
#define RT_MAX 40   // max sum over experts of ceil(count/128) is 39; pad to 40

typedef unsigned short u16;
typedef unsigned int u32;
typedef __attribute__((ext_vector_type(8))) short bf16x8;
typedef __attribute__((ext_vector_type(4))) float f32x4;

#define AS1 __attribute__((address_space(1)))
#define AS3 __attribute__((address_space(3)))

// fragment/source granule swizzle (verified R9: SQ_LDS_BANK_CONFLICT = 0)
#define SWZ(r) (((r) >> 1) & 3)

static __device__ __forceinline__ u16 f2bf(float f) {
    u32 u = __float_as_uint(f);
    u32 r = u + 0x7fffu + ((u >> 16) & 1u);
    return (u16)(r >> 16);
}

static __device__ __forceinline__ u32 pk2bf(float lo, float hi) {
    __hip_bfloat162 h = __float22bfloat162_rn(make_float2(lo, hi));
    return *(u32*)&h;
}

// ---------------- router: fp32 argmax over 8 experts ----------------
__global__ __launch_bounds__(256) void k_router(const float* __restrict__ x,
                                                const float* __restrict__ Wg,
                                                int* __restrict__ ids,
                                                int* __restrict__ counts) {
    int wave = threadIdx.x >> 6;
    int lane = threadIdx.x & 63;
    int t = blockIdx.x * 4 + wave;

    const float4* xr = (const float4*)(x + (size_t)t * DIMSZ);
    float4 xv[4];
#pragma unroll
    for (int j = 0; j < 4; j++) xv[j] = xr[j * 64 + lane];

    float s[NE];
#pragma unroll
    for (int e = 0; e < NE; e++) {
        const float4* wr = (const float4*)(Wg + (size_t)e * DIMSZ);
        float p = 0.f;
#pragma unroll
        for (int j = 0; j < 4; j++) {
            float4 w = wr[j * 64 + lane];
            p += xv[j].x * w.x + xv[j].y * w.y + xv[j].z * w.z + xv[j].w * w.w;
        }
#pragma unroll
        for (int m = 32; m >= 1; m >>= 1) p += __shfl_xor(p, m, 64);
        s[e] = p;
    }
    if (lane == 0) {
        int best = 0;
#pragma unroll
        for (int e = 1; e < NE; e++) if (s[e] > s[best]) best = e;  // first-max tiebreak
        ids[t] = best;
        atomicAdd(&counts[best], 1);
    }
}

// ---------------- weight transpose tile: fp32 [K][N] -> bf16 [N][K] (verified R8-R10) ----
static __device__ __forceinline__ void wt_body(const float* __restrict__ src,
                                               u16* __restrict__ dst,
                                               int K, int N, int kt, int nt,
                                               u32 (*T)[65]) {
    int tid = threadIdx.x;
#pragma unroll
    for (int pass = 0; pass < 2; pass++) {
        int kp = (tid >> 4) + pass * 16;
        int nc = (tid & 15) * 4;
        const float* r0 = src + (size_t)(kt * 64 + 2 * kp) * N + nt * 64 + nc;
        float4 a = *(const float4*)r0;
        float4 b = *(const float4*)(r0 + N);
        T[kp][nc + 0] = pk2bf(a.x, b.x);
        T[kp][nc + 1] = pk2bf(a.y, b.y);
        T[kp][nc + 2] = pk2bf(a.z, b.z);
        T[kp][nc + 3] = pk2bf(a.w, b.w);
    }
    __syncthreads();
    int n = tid >> 2;
    int sb = (tid & 3) * 8;
    u16* orow = dst + (size_t)(nt * 64 + n) * K + kt * 64;
#pragma unroll
    for (int p = 0; p < 2; p++) {
        int s = sb + p * 4;
        *(uint4*)(orow + 2 * s) = make_uint4(T[s][n], T[s + 1][n], T[s + 2][n], T[s + 3][n]);
    }
}

// ---------------- grouped GEMM body: 128x128 tile, BK=32, 4 waves ----------------
// R9-verified staging/swizzle; NEW: 2-buffer counted pipeline (32KB LDS -> 5 blocks/CU),
// depth-1 prefetch, WAITV(4) in the loop (never 0), 2 barriers/iter.
//   iter kk: STAGE(buf[(kk+1)&1], kk+1)   // buffer freed by end-BAR of iter kk-1
//            WAITV(4) -> stage(kk) landed; BAR -> collective
//            COMPUTE(buf[kk&1]); BAR      // reads done before iter kk+1 overwrites
// offs computed locally from counts (k_scan eliminated).
template <int KDIM, int NDIM, int EPI, int KSPLIT>
static __device__ __forceinline__ void gemm_body(int bid,
                                                 const u16* __restrict__ A,
                                                 const u16* __restrict__ Wt,
                                                 const float* __restrict__ biasAll,
                                                 const int* __restrict__ counts,
                                                 const int* __restrict__ perm,
                                                 u16* __restrict__ Hout,
                                                 float* __restrict__ Fout,
                                                 u16* lds /* 16384 u16 = 32KB */) {
    constexpr int NT = NDIM / 128;
    constexpr int NREST = NT * KSPLIT;
    constexpr int NWG = RT_MAX * NREST;   // 1280 for both instantiations
    constexpr int CPX = NWG / 8;
    constexpr int KL = KDIM / KSPLIT;
    constexpr int NKL = KL / 32;          // 32 for both
    int wid = (bid & 7) * CPX + (bid >> 3);   // bijective XCD swizzle
    int x = wid / NREST;                       // row-tile SLOW (A panel L2-resident)
    int rest = wid % NREST;
    int ks = rest % KSPLIT;
    int n0 = (rest / KSPLIT) * 128;
    int kbase = ks * KL;

    // map x -> (expert, local row tile); offs accumulated from counts
    int e = -1, lrt = 0, a0 = 0, off_e = 0, cum = 0;
#pragma unroll
    for (int i = 0; i < NE; i++) {
        int c = counts[i];
        int rt = (c + 127) >> 7;
        if (e < 0 && x < a0 + rt) { e = i; lrt = x - a0; off_e = cum; }
        a0 += rt;
        cum += c;
    }
    if (e < 0) return;
    int row0 = off_e + lrt * 128;
    int nrows = off_e + counts[e] - row0;
    if (nrows > 128) nrows = 128;

    u16* Asb[2] = { lds,        lds + 8192 };   // [128][32] each
    u16* Bsb[2] = { lds + 4096, lds + 12288 };

    int tid = threadIdx.x;
    int lane = tid & 63;
    int wave = tid >> 6;
    int wr = wave >> 1, wc = wave & 1;

    // staging: granule g = p*256+tid -> LDS row r=g>>2, slot g&3; source holds
    // global k-granule slot^SWZ(r) (inverse-swizzled source, rule #21)
    const u16* srcA[2];
    const u16* srcB[2];
#pragma unroll
    for (int p = 0; p < 2; p++) {
        int g = p * 256 + tid;
        int r = g >> 2, slot = g & 3;
        int rc = r < nrows ? r : nrows - 1;
        int kg = (slot ^ SWZ(r)) * 8;
        srcA[p] = A + (size_t)(row0 + rc) * KDIM + kbase + kg;
        srcB[p] = Wt + (size_t)e * NDIM * KDIM + (size_t)(n0 + r) * KDIM + kbase + kg;
    }

    f32x4 acc[4][4] = {};
    int fr = lane & 15, fc = lane >> 4;

#define STAGE(BUF, KT)                                                          \
    {                                                                           \
        _Pragma("unroll")                                                       \
        for (int p = 0; p < 2; p++) {                                           \
            __builtin_amdgcn_global_load_lds(                                   \
                (const AS1 void*)(srcA[p] + (size_t)(KT) * 32),                 \
                (AS3 void*)(Asb[BUF] + (p * 256 + wave * 64) * 8), 16, 0, 0);   \
            __builtin_amdgcn_global_load_lds(                                   \
                (const AS1 void*)(srcB[p] + (size_t)(KT) * 32),                 \
                (AS3 void*)(Bsb[BUF] + (p * 256 + wave * 64) * 8), 16, 0, 0);   \
        }                                                                       \
    }

#define COMPUTE(BUF)                                                            \
    {                                                                           \
        bf16x8 af[4], bfr[4];                                                   \
        _Pragma("unroll")                                                       \
        for (int m = 0; m < 4; m++) {                                           \
            int r = wr * 64 + m * 16 + fr;                                      \
            af[m] = *(const bf16x8*)(Asb[BUF] + r * 32 + (fc ^ SWZ(r)) * 8);    \
        }                                                                       \
        _Pragma("unroll")                                                       \
        for (int n = 0; n < 4; n++) {                                           \
            int N = wc * 64 + n * 16 + fr;                                      \
            bfr[n] = *(const bf16x8*)(Bsb[BUF] + N * 32 + (fc ^ SWZ(N)) * 8);   \
        }                                                                       \
        _Pragma("unroll")                                                       \
        for (int m = 0; m < 4; m++)                                             \
            _Pragma("unroll")                                                   \
            for (int n = 0; n < 4; n++)                                         \
                acc[m][n] = __builtin_amdgcn_mfma_f32_16x16x32_bf16(af[m], bfr[n], acc[m][n], 0, 0, 0); \
    }

#define WAITV(N) asm volatile("s_waitcnt vmcnt(" #N ")" ::: "memory")
#define BAR()    __builtin_amdgcn_s_barrier()
#define SCB()    __builtin_amdgcn_sched_barrier(0)

    STAGE(0, 0);
    for (int kk = 0; kk < NKL - 1; kk++) {
        STAGE((kk + 1) & 1, kk + 1);
        WAITV(4);              // stage(kk) landed for this wave
        BAR();                 // collective
        SCB();
        COMPUTE(kk & 1);
        BAR();                 // reads done before next iter's STAGE overwrites
        SCB();
    }
    WAITV(0);
    BAR();
    SCB();
    COMPUTE((NKL - 1) & 1);

#undef STAGE
#undef COMPUTE
#undef WAITV
#undef BAR
#undef SCB

    // epilogue (C/D layout: col = lane&15, row = (lane>>4)*4 + j)
    int cb = lane & 15;
    int rq = lane >> 4;
#pragma unroll
    for (int m = 0; m < 4; m++) {
        int rbase = wr * 64 + m * 16 + rq * 4;
#pragma unroll
        for (int n = 0; n < 4; n++) {
            int col = n0 + wc * 64 + n * 16 + cb;
            float bias = (EPI == 2 && ks != 0) ? 0.f : biasAll[(size_t)e * NDIM + col];
#pragma unroll
            for (int j = 0; j < 4; j++) {
                int r = rbase + j;
                if (r < nrows) {
                    float v = acc[m][n][j] + bias;
                    int p = row0 + r;
                    if (EPI == 1) {
                        float g = 0.5f * v * (1.0f + erff(v * 0.70710678118654752f));
                        Hout[(size_t)p * NDIM + col] = f2bf(g);
                    } else {
                        atomicAdd(&Fout[(size_t)perm[p] * NDIM + col], v);
                    }
                }
            }
        }
    }
}

// ---------------- k_pre: gather (with local scan) || W1 transpose ----------------
__global__ __launch_bounds__(256) void k_pre(const float* __restrict__ x,
                                             const int* __restrict__ ids,
                                             const int* __restrict__ counts,
                                             int* __restrict__ cursor,
                                             int* __restrict__ perm,
                                             u16* __restrict__ Xg,
                                             const float* __restrict__ W1,
                                             u16* __restrict__ W1T) {
    __shared__ u32 T[32][65];
    __shared__ int sp;
    int bid = blockIdx.x;
    if (bid < NTOK) {
        int t = bid;
        if (threadIdx.x == 0) {
            int e = ids[t];
            int off = 0;
            for (int i = 0; i < e; i++) off += counts[i];
            int p = off + atomicAdd(&cursor[e], 1);
            perm[p] = t;
            sp = p;
        }
        __syncthreads();
        int p = sp;
        float4 v = ((const float4*)(x + (size_t)t * DIMSZ))[threadIdx.x];
        *(uint2*)(Xg + (size_t)p * DIMSZ + threadIdx.x * 4) =
            make_uint2(pk2bf(v.x, v.y), pk2bf(v.z, v.w));
    } else {
        int b = bid - NTOK;                 // [0, 8192): W1 tiles
        int e = b >> 10, t = b & 1023;
        int kt = t >> 6, nt = t & 63;       // K=1024: 16 k-tiles; N=4096: 64 n-tiles
        wt_body(W1 + (size_t)e * 1024 * 4096, W1T + (size_t)e * 4096 * 1024,
                1024, 4096, kt, nt, T);
    }
}

// ---------------- k_mid: GEMM1 (blocks 0..1279) || W2 transpose || out-zero ----------------
__global__ __launch_bounds__(256, 5) void k_mid(const u16* __restrict__ Xg,
                                                const u16* __restrict__ W1T,
                                                const float* __restrict__ b1,
                                                const int* __restrict__ counts,
                                                const int* __restrict__ perm,
                                                u16* __restrict__ H,
                                                const float* __restrict__ W2,
                                                u16* __restrict__ W2T,
                                                float* __restrict__ out) {
    __shared__ alignas(16) u16 LDS[16384];   // 32KB: gemm dbuf / transpose T (8.3KB)
    int bid = blockIdx.x;
    if (bid < 1280) {
        gemm_body<DIMSZ, HID, 1, 1>(bid, Xg, W1T, b1, counts, perm, H, (float*)nullptr, LDS);
    } else if (bid < 1280 + 8192) {
        int b = bid - 1280;
        int e = b >> 10, t = b & 1023;
        int kt = t >> 4, nt = t & 15;       // K=4096: 64 k-tiles; N=1024: 16 n-tiles
        wt_body(W2 + (size_t)e * 4096 * 1024, W2T + (size_t)e * 1024 * 4096,
                4096, 1024, kt, nt, (u32(*)[65])LDS);
    } else {
        int b = bid - (1280 + 8192);        // [0, 4096): zero d_out (G2 atomics)
        int i = b * 1024 + threadIdx.x * 4;
        *(float4*)(out + i) = make_float4(0.f, 0.f, 0.f, 0.f);
    }
}

// ---------------- k_g2: GEMM2, KSPLIT=4 -> 1280 blocks -> 5/CU ----------------
__global__ __launch_bounds__(256, 5) void k_g2(const u16* __restrict__ H,
                                               const u16* __restrict__ W2T,
                                               const float* __restrict__ b2,
                                               const int* __restrict__ counts,
                                               const int* __restrict__ perm,
                                               float* __restrict__ out) {
    __shared__ alignas(16) u16 LDS[16384];
    gemm_body<HID, DIMSZ, 2, 4>(blockIdx.x, H, W2T, b2, counts, perm,
                                (u16*)nullptr, out, LDS);
}

extern "C" void kernel_launch(void* const* d_in, const int* in_sizes, int n_in,
                              void* d_out, int out_size, void* d_ws, size_t ws_size,
                              hipStream_t stream) {
    const float* x  = (const float*)d_in[0];
    const float* Wg = (const float*)d_in[1];
    const float* W1 = (const float*)d_in[2];
    const float* b1 = (const float*)d_in[3];
    const float* W2 = (const float*)d_in[4];
    const float* b2 = (const float*)d_in[5];
    float* out = (float*)d_out;

    char* ws = (char*)d_ws;
    int* ids    = (int*)(ws + 0);          // 16384 B
    int* counts = (int*)(ws + 16384);      // 32 B
    int* cursor = (int*)(ws + 16512);      // 32 B
    int* perm   = (int*)(ws + 16576);      // 16384 B

    u16* Xg   = (u16*)(ws + 65536);                                  // 8 MiB
    u16* H    = (u16*)(ws + 65536 + 8388608);                        // 32 MiB
    u16* W1T  = (u16*)(ws + 65536 + 8388608 + 33554432);             // 64 MiB
    u16* W2T  = (u16*)(ws + 65536 + 8388608 + 33554432 + 67108864);  // 64 MiB

    hipMemsetAsync(ws + 16384, 0, 192, stream);   // counts + cursor
    k_router<<<dim3(NTOK / 4), dim3(256), 0, stream>>>(x, Wg, ids, counts);
    k_pre<<<dim3(NTOK + 8192), dim3(256), 0, stream>>>(x, ids, counts, cursor, perm, Xg, W1, W1T);
    k_mid<<<dim3(1280 + 8192 + 4096), dim3(256), 0, stream>>>(Xg, W1T, b1, counts, perm, H, W2, W2T, out);
    k_g2<<<dim3(1280), dim3(256), 0, stream>>>(H, W2T, b2, counts, perm, out);
}

// Round 12
// 370.849 us; speedup vs baseline: 1.2237x; 1.2237x over previous
//
#include <hip/hip_runtime.h>
#include <hip/hip_bf16.h>
#include <math.h>

#define NTOK 4096
#define DIMSZ 1024
#define HID 4096
#define NE 8
#define RT256 24   // max sum over experts of ceil(count/256) = 16 + 8 pad

typedef unsigned short u16;
typedef unsigned int u32;
typedef __attribute__((ext_vector_type(8))) short bf16x8;
typedef __attribute__((ext_vector_type(4))) float f32x4;

#define AS1 __attribute__((address_space(1)))
#define AS3 __attribute__((address_space(3)))

// granule swizzle (verified R9: SQ_LDS_BANK_CONFLICT = 0)
#define SWZ(r) (((r) >> 1) & 3)

static __device__ __forceinline__ u16 f2bf(float f) {
    u32 u = __float_as_uint(f);
    u32 r = u + 0x7fffu + ((u >> 16) & 1u);
    return (u16)(r >> 16);
}

static __device__ __forceinline__ u32 pk2bf(float lo, float hi) {
    __hip_bfloat162 h = __float22bfloat162_rn(make_float2(lo, hi));
    return *(u32*)&h;
}

__global__ void k_init(int* counts, int* cursor) {
    if (threadIdx.x < NE) { counts[threadIdx.x] = 0; cursor[threadIdx.x] = 0; }
}

__global__ void k_zero(float* p) {
    int i = blockIdx.x * 1024 + threadIdx.x * 4;
    *(float4*)(p + i) = make_float4(0.f, 0.f, 0.f, 0.f);
}

__global__ __launch_bounds__(256) void k_router(const float* __restrict__ x,
                                                const float* __restrict__ Wg,
                                                int* __restrict__ ids,
                                                int* __restrict__ counts) {
    int wave = threadIdx.x >> 6;
    int lane = threadIdx.x & 63;
    int t = blockIdx.x * 4 + wave;

    const float4* xr = (const float4*)(x + (size_t)t * DIMSZ);
    float4 xv[4];
#pragma unroll
    for (int j = 0; j < 4; j++) xv[j] = xr[j * 64 + lane];

    float s[NE];
#pragma unroll
    for (int e = 0; e < NE; e++) {
        const float4* wr = (const float4*)(Wg + (size_t)e * DIMSZ);
        float p = 0.f;
#pragma unroll
        for (int j = 0; j < 4; j++) {
            float4 w = wr[j * 64 + lane];
            p += xv[j].x * w.x + xv[j].y * w.y + xv[j].z * w.z + xv[j].w * w.w;
        }
#pragma unroll
        for (int m = 32; m >= 1; m >>= 1) p += __shfl_xor(p, m, 64);
        s[e] = p;
    }
    if (lane == 0) {
        int best = 0;
#pragma unroll
        for (int e = 1; e < NE; e++) if (s[e] > s[best]) best = e;
        ids[t] = best;
        atomicAdd(&counts[best], 1);
    }
}

__global__ void k_scan(const int* __restrict__ counts, int* __restrict__ offs) {
    if (threadIdx.x == 0) {
        int a = 0;
        for (int e = 0; e < NE; e++) { offs[e] = a; a += counts[e]; }
    }
}

__global__ __launch_bounds__(256) void k_gather(const float* __restrict__ x,
                                                const int* __restrict__ ids,
                                                const int* __restrict__ offs,
                                                int* __restrict__ cursor,
                                                int* __restrict__ perm,
                                                u16* __restrict__ Xg) {
    int t = blockIdx.x;
    __shared__ int sp;
    if (threadIdx.x == 0) {
        int e = ids[t];
        int p = offs[e] + atomicAdd(&cursor[e], 1);
        perm[p] = t;
        sp = p;
    }
    __syncthreads();
    int p = sp;
    float4 v = ((const float4*)(x + (size_t)t * DIMSZ))[threadIdx.x];
    *(uint2*)(Xg + (size_t)p * DIMSZ + threadIdx.x * 4) =
        make_uint2(pk2bf(v.x, v.y), pk2bf(v.z, v.w));
}

// weight transpose+convert: fp32 [E][K][N] -> bf16 [E][N][K] (R8-R10 verified)
__global__ __launch_bounds__(256) void k_wt(const float* __restrict__ W1,
                                            const float* __restrict__ W2,
                                            u16* __restrict__ W1T,
                                            u16* __restrict__ W2T) {
    int bid = blockIdx.x;
    const float* src;
    u16* dst;
    int K, N, kt, nt;
    if (bid < 8192) {
        int e = bid >> 10, t = bid & 1023;
        kt = t >> 6; nt = t & 63;
        src = W1 + (size_t)e * 1024 * 4096;
        dst = W1T + (size_t)e * 4096 * 1024;
        K = 1024; N = 4096;
    } else {
        int b = bid - 8192;
        int e = b >> 10, t = b & 1023;
        kt = t >> 4; nt = t & 15;
        src = W2 + (size_t)e * 4096 * 1024;
        dst = W2T + (size_t)e * 1024 * 4096;
        K = 4096; N = 1024;
    }
    __shared__ u32 T[32][65];
    int tid = threadIdx.x;
#pragma unroll
    for (int pass = 0; pass < 2; pass++) {
        int kp = (tid >> 4) + pass * 16;
        int nc = (tid & 15) * 4;
        const float* r0 = src + (size_t)(kt * 64 + 2 * kp) * N + nt * 64 + nc;
        float4 a = *(const float4*)r0;
        float4 b = *(const float4*)(r0 + N);
        T[kp][nc + 0] = pk2bf(a.x, b.x);
        T[kp][nc + 1] = pk2bf(a.y, b.y);
        T[kp][nc + 2] = pk2bf(a.z, b.z);
        T[kp][nc + 3] = pk2bf(a.w, b.w);
    }
    __syncthreads();
    int n = tid >> 2;
    int sb = (tid & 3) * 8;
    u16* orow = dst + (size_t)(nt * 64 + n) * K + kt * 64;
#pragma unroll
    for (int p = 0; p < 2; p++) {
        int s = sb + p * 4;
        *(uint4*)(orow + 2 * s) = make_uint4(T[s][n], T[s + 1][n], T[s + 2][n], T[s + 3][n]);
    }
}

// ---------------- grouped GEMM: 256x128 tile, BK=32, 8 waves ----------------
// R9-exact sync structure (3-buffer depth-2 counted pipeline, WAITV(ops-per-stage),
// one BAR cluster per iter, SWZ granule swizzle, row-tile SLOW axis). ONLY change
// vs R9: M-tile 128->256 (halves per-XCD B-panel re-reads: 320MB->~192MB L3->L2
// fill, the measured 2.6TB/s invariant both R9 GEMMs sat at).
// Per stage: 3 vmem ops/thread (2xA granules, 1xB granule) -> WAITV(3).
template <int KDIM, int NDIM, int EPI, int KSPLIT>
__global__ __launch_bounds__(512, 4) void k_gemm(const u16* __restrict__ A,
                                                 const u16* __restrict__ Wt,
                                                 const float* __restrict__ biasAll,
                                                 const int* __restrict__ counts,
                                                 const int* __restrict__ offs,
                                                 const int* __restrict__ perm,
                                                 u16* __restrict__ Hout,
                                                 float* __restrict__ Fout) {
    constexpr int NT = NDIM / 128;
    constexpr int NREST = NT * KSPLIT;
    constexpr int NWG = RT256 * NREST;   // 768 (G1) / 384 (G2), %8==0
    constexpr int CPX = NWG / 8;
    constexpr int KL = KDIM / KSPLIT;
    constexpr int NKL = KL / 32;         // 32 (G1) / 64 (G2)
    int bid = blockIdx.x;
    int wid = (bid & 7) * CPX + (bid >> 3);   // bijective XCD swizzle
    int x = wid / NREST;                       // row-tile SLOW (A panel L2-resident)
    int rest = wid % NREST;
    int ks = rest % KSPLIT;
    int n0 = (rest / KSPLIT) * 128;
    int kbase = ks * KL;

    // map x -> (expert, local 256-row tile)
    int e = -1, lrt = 0, a0 = 0;
#pragma unroll
    for (int i = 0; i < NE; i++) {
        int rt = (counts[i] + 255) >> 8;
        if (e < 0 && x < a0 + rt) { e = i; lrt = x - a0; }
        a0 += rt;
    }
    if (e < 0) return;
    int row0 = offs[e] + lrt * 256;
    int nrows = offs[e] + counts[e] - row0;
    if (nrows > 256) nrows = 256;

    __shared__ alignas(16) u16 Asb[3][256][32];   // 48KB rotating triple buffer
    __shared__ alignas(16) u16 Bsb[3][128][32];   // 24KB

    int tid = threadIdx.x;          // 0..511
    int lane = tid & 63;
    int wave = tid >> 6;            // 0..7
    int wr = wave >> 1;             // 0..3: 64-row quarter of 256
    int wc = wave & 1;              // 0..1: 64-col half of 128
    int fr = lane & 15, fc = lane >> 4;

    // staging sources (rule #21: linear LDS dest, inverse-swizzled global source)
    // A: granules g = c*512 + tid (c=0,1), r=g>>2 in [0,256), slot=g&3
    // B: granules g = tid, r=g>>2 in [0,128)
    const u16* srcA[2];
    const u16* srcB;
#pragma unroll
    for (int c = 0; c < 2; c++) {
        int g = c * 512 + tid;
        int r = g >> 2, slot = g & 3;
        int rc = r < nrows ? r : nrows - 1;
        srcA[c] = A + (size_t)(row0 + rc) * KDIM + kbase + (slot ^ SWZ(r)) * 8;
    }
    {
        int r = tid >> 2, slot = tid & 3;
        srcB = Wt + (size_t)e * NDIM * KDIM + (size_t)(n0 + r) * KDIM + kbase + (slot ^ SWZ(r)) * 8;
    }

    f32x4 acc[4][4] = {};

    u16 *A0 = &Asb[0][0][0], *A1 = &Asb[1][0][0], *A2 = &Asb[2][0][0];
    u16 *B0 = &Bsb[0][0][0], *B1 = &Bsb[1][0][0], *B2 = &Bsb[2][0][0];

#define STAGE(AD, BD, KT)                                                       \
    {                                                                           \
        _Pragma("unroll")                                                       \
        for (int c = 0; c < 2; c++) {                                           \
            __builtin_amdgcn_global_load_lds(                                   \
                (const AS1 void*)(srcA[c] + (size_t)(KT) * 32),                 \
                (AS3 void*)((AD) + (c * 512 + wave * 64) * 8), 16, 0, 0);       \
        }                                                                       \
        __builtin_amdgcn_global_load_lds(                                       \
            (const AS1 void*)(srcB + (size_t)(KT) * 32),                        \
            (AS3 void*)((BD) + (wave * 64) * 8), 16, 0, 0);                     \
    }

#define COMPUTE(AP, BP)                                                         \
    {                                                                           \
        bf16x8 af[4], bfr[4];                                                   \
        _Pragma("unroll")                                                       \
        for (int m = 0; m < 4; m++) {                                           \
            int r = wr * 64 + m * 16 + fr;                                      \
            af[m] = *(const bf16x8*)((AP) + r * 32 + (fc ^ SWZ(r)) * 8);        \
        }                                                                       \
        _Pragma("unroll")                                                       \
        for (int n = 0; n < 4; n++) {                                           \
            int N = wc * 64 + n * 16 + fr;                                      \
            bfr[n] = *(const bf16x8*)((BP) + N * 32 + (fc ^ SWZ(N)) * 8);       \
        }                                                                       \
        _Pragma("unroll")                                                       \
        for (int m = 0; m < 4; m++)                                             \
            _Pragma("unroll")                                                   \
            for (int n = 0; n < 4; n++)                                         \
                acc[m][n] = __builtin_amdgcn_mfma_f32_16x16x32_bf16(af[m], bfr[n], acc[m][n], 0, 0, 0); \
    }

#define WAITV(N) asm volatile("s_waitcnt vmcnt(" #N ")" ::: "memory")
#define BAR()    __builtin_amdgcn_s_barrier()
#define SCB()    __builtin_amdgcn_sched_barrier(0)

    // prologue: issue tiles 0 and 1 (3 vmem ops each)
    STAGE(A0, B0, 0);
    STAGE(A1, B1, 1);

    for (int kk = 0; kk < NKL - 2; kk++) {
        WAITV(3);              // stage(kk) landed for this wave (stage(kk+1) in flight)
        BAR();                 // collective
        SCB();
        STAGE(A2, B2, kk + 2); // overwrites buffer last read at COMPUTE(kk-1)
        COMPUTE(A0, B0);
        u16* t;
        t = A0; A0 = A1; A1 = A2; A2 = t;
        t = B0; B0 = B1; B1 = B2; B2 = t;
    }
    WAITV(3);
    BAR();
    SCB();
    COMPUTE(A0, B0);
    WAITV(0);
    BAR();
    SCB();
    COMPUTE(A1, B1);

#undef STAGE
#undef COMPUTE
#undef WAITV
#undef BAR
#undef SCB

    // epilogue (C/D layout: col = lane&15, row = (lane>>4)*4 + j)
    int cb = lane & 15;
    int rq = lane >> 4;
#pragma unroll
    for (int m = 0; m < 4; m++) {
        int rbase = wr * 64 + m * 16 + rq * 4;
#pragma unroll
        for (int n = 0; n < 4; n++) {
            int col = n0 + wc * 64 + n * 16 + cb;
            float bias = (EPI == 2 && ks != 0) ? 0.f : biasAll[(size_t)e * NDIM + col];
#pragma unroll
            for (int j = 0; j < 4; j++) {
                int r = rbase + j;
                if (r < nrows) {
                    float v = acc[m][n][j] + bias;
                    int p = row0 + r;
                    if (EPI == 1) {
                        float g = 0.5f * v * (1.0f + erff(v * 0.70710678118654752f));
                        Hout[(size_t)p * NDIM + col] = f2bf(g);
                    } else {
                        atomicAdd(&Fout[(size_t)perm[p] * NDIM + col], v);
                    }
                }
            }
        }
    }
}

extern "C" void kernel_launch(void* const* d_in, const int* in_sizes, int n_in,
                              void* d_out, int out_size, void* d_ws, size_t ws_size,
                              hipStream_t stream) {
    const float* x  = (const float*)d_in[0];
    const float* Wg = (const float*)d_in[1];
    const float* W1 = (const float*)d_in[2];
    const float* b1 = (const float*)d_in[3];
    const float* W2 = (const float*)d_in[4];
    const float* b2 = (const float*)d_in[5];
    float* out = (float*)d_out;

    char* ws = (char*)d_ws;
    int* ids    = (int*)(ws + 0);
    int* counts = (int*)(ws + 16384);
    int* offs   = (int*)(ws + 16448);
    int* cursor = (int*)(ws + 16512);
    int* perm   = (int*)(ws + 16576);

    u16* Xg   = (u16*)(ws + 65536);                                  // 8 MiB
    u16* H    = (u16*)(ws + 65536 + 8388608);                        // 32 MiB
    u16* W1T  = (u16*)(ws + 65536 + 8388608 + 33554432);             // 64 MiB
    u16* W2T  = (u16*)(ws + 65536 + 8388608 + 33554432 + 67108864);  // 64 MiB

    k_init<<<dim3(1), dim3(64), 0, stream>>>(counts, cursor);
    k_router<<<dim3(NTOK / 4), dim3(256), 0, stream>>>(x, Wg, ids, counts);
    k_scan<<<dim3(1), dim3(64), 0, stream>>>(counts, offs);
    k_gather<<<dim3(NTOK), dim3(256), 0, stream>>>(x, ids, offs, cursor, perm, Xg);
    k_wt<<<dim3(16384), dim3(256), 0, stream>>>(W1, W2, W1T, W2T);
    k_zero<<<dim3(NTOK * DIMSZ / 1024), dim3(256), 0, stream>>>(out);
    k_gemm<DIMSZ, HID, 1, 1><<<dim3(RT256 * (HID / 128)), dim3(512), 0, stream>>>(
        Xg, W1T, b1, counts, offs, perm, H, (float*)nullptr);
    k_gemm<HID, DIMSZ, 2, 2><<<dim3(RT256 * (DIMSZ / 128) * 2), dim3(512), 0, stream>>>(
        H, W2T, b2, counts, offs, perm, (u16*)nullptr, out);
}